// Round 8
// baseline (864.167 us; speedup 1.0000x reference)
//
#include <hip/hip_runtime.h>
#include <math.h>

#define TSAMP 30
#define NGRP  5          // t-groups
#define TPG   6          // t's per group (NGRP*TPG == TSAMP)
#define FEPS  1e-15f

// softplus(x) = log1p(exp(x)), stable, 1 exp + 1 log
__device__ __forceinline__ float softplus(float x) {
    return fmaxf(x, 0.0f) + __logf(1.0f + __expf(-fabsf(x)));
}

// Fused kernel: grid = NGRP * pblk. g = bid % NGRP owns t in [g*TPG, g*TPG+TPG).
// Body = R7's proven single-pair form (65.2 us). Last block (ticket) does the
// final reduce + epilogue, saving 2 launches + k2/k3.
// __launch_bounds__(256,4): VGPR cap 128 — R5/R6 lesson: the default budget
// (48 VGPR) serialized the load burst to ~1-2 outstanding/wave -> 163 GB/s.
__global__ __launch_bounds__(256, 4) void bcc_fused(
    const float4* __restrict__ logit4,   // [npair]
    const float2* __restrict__ var2,     // [npair]
    const int2*   __restrict__ true2,    // [npair]
    const float4* __restrict__ noise4,   // [TSAMP][npair]
    float* __restrict__ partial,         // [32][pblk]
    unsigned int* __restrict__ counter,  // [1], zeroed before launch
    float* __restrict__ out,
    int npair, int pblk, float invN)
{
    const int g     = blockIdx.x % NGRP;
    const int pb    = blockIdx.x / NGRP;
    const int tbase = g * TPG;

    float acc[TPG];
    #pragma unroll
    for (int k = 0; k < TPG; ++k) acc[k] = 0.0f;
    float u_acc = 0.0f, vd_acc = 0.0f;

    const int pstride = pblk * 256;
    const float4* nbase = noise4 + (size_t)tbase * (size_t)npair;

    for (int p = pb * 256 + threadIdx.x; p < npair; p += pstride) {
        const float4 lg = logit4[p];
        const float2 v  = var2[p];
        const int2   yy = true2[p];

        // issue all 6 noise loads before the param-dependent math
        float4 nz[TPG];
        #pragma unroll
        for (int k = 0; k < TPG; ++k)
            nz[k] = nbase[(size_t)k * (size_t)npair + p];

        const float sg0 = yy.x ? 1.0f : -1.0f;
        const float d0  = sg0 * (lg.x - lg.y);
        const float ss0 = sg0 * (__fsqrt_rn(v.x) + FEPS);
        const float sg1 = yy.y ? 1.0f : -1.0f;
        const float d1  = sg1 * (lg.z - lg.w);
        const float ss1 = sg1 * (__fsqrt_rn(v.y) + FEPS);

        if (g == 0) {
            vd_acc += (__expf(v.x) - 1.0f) + (__expf(v.y) - 1.0f);
            u_acc  -= softplus(d0) + softplus(d1);
        }

        #pragma unroll
        for (int k = 0; k < TPG; ++k) {
            const float x0 = fmaf(ss0, nz[k].x - nz[k].y, d0);
            const float x1 = fmaf(ss1, nz[k].z - nz[k].w, d1);
            acc[k] -= softplus(x0) + softplus(x1);
        }
    }

    // ---- block reduce TPG+2 slots (deterministic) ----
    __shared__ float s_part[4][TPG + 2];
    const int lane = threadIdx.x & 63;
    const int wav  = threadIdx.x >> 6;
    #pragma unroll
    for (int a = 0; a < TPG + 2; ++a) {
        float vv = (a < TPG) ? acc[a] : ((a == TPG) ? u_acc : vd_acc);
        #pragma unroll
        for (int off = 32; off >= 1; off >>= 1)
            vv += __shfl_down(vv, off, 64);
        if (lane == 0) s_part[wav][a] = vv;
    }
    __syncthreads();
    if (threadIdx.x < TPG + 2) {
        const int a = threadIdx.x;
        const float s = s_part[0][a] + s_part[1][a] + s_part[2][a] + s_part[3][a];
        if (a < TPG)
            partial[(size_t)(tbase + a) * (size_t)pblk + pb] = s;
        else if (g == 0)
            partial[(size_t)(TSAMP + (a - TPG)) * (size_t)pblk + pb] = s;
    }

    // ---- last-block-done: final reduce + epilogue ----
    __threadfence();   // release our partial writes device-wide
    __shared__ unsigned s_ticket;
    if (threadIdx.x == 0)
        s_ticket = __hip_atomic_fetch_add(counter, 1u, __ATOMIC_ACQ_REL,
                                          __HIP_MEMORY_SCOPE_AGENT);
    __syncthreads();
    if (s_ticket == (unsigned)(gridDim.x - 1)) {
        __threadfence();   // acquire: see all blocks' partial writes

        const int a = threadIdx.x >> 3;   // slot 0..31
        const int k = threadIdx.x & 7;    // 8 threads per slot
        float s = 0.0f;
        for (int j = k; j < pblk; j += 8)
            s += partial[(size_t)a * (size_t)pblk + j];
        s += __shfl_down(s, 4, 64);
        s += __shfl_down(s, 2, 64);
        s += __shfl_down(s, 1, 64);
        __shared__ float res[32];
        if (k == 0) res[a] = s;
        __syncthreads();
        if (threadIdx.x == 0) {
            const float U  = -res[30] * invN;          // undistorted_loss
            const float vd =  res[31] * invN;          // mean variance_depressor
            float mc_sum = 0.0f;
            #pragma unroll
            for (int t = 0; t < TSAMP; ++t) {
                const float D = -res[t] * invN;        // distorted_loss[t]
                const float x = U - D;
                const float e = (x > 0.0f) ? x : expm1f(x);   // elu(x)
                mc_sum += -e;                           // monte_carlo[t]
            }
            const float variance_loss = (mc_sum / (float)TSAMP) * U;
            out[0] = variance_loss + U + vd;
        }
    }
}

extern "C" void kernel_launch(void* const* d_in, const int* in_sizes, int n_in,
                              void* d_out, int out_size, void* d_ws, size_t ws_size,
                              hipStream_t stream) {
    const float* logit = (const float*)d_in[0];   // [N,2] f32
    const float* var   = (const float*)d_in[1];   // [N,1] f32
    const int*   tru   = (const int*)d_in[2];     // [N]   i32
    const float* noise = (const float*)d_in[3];   // [30,N,2] f32
    float* out = (float*)d_out;

    const int N = in_sizes[1];          // var has N elements
    const int npair = N / 2;

    int pblk = 1024;                    // 2 grid-stride iterations per thread
    {
        int maxp = (npair + 255) / 256;
        if (pblk > maxp) pblk = maxp;
        const size_t need = (size_t)32 * (size_t)pblk * sizeof(float) + 64;
        if (ws_size < need) {
            pblk = (int)((ws_size - 64) / (32 * sizeof(float)));
            if (pblk < 1) pblk = 1;
        }
    }
    float* partial = (float*)d_ws;                              // [32][pblk]
    unsigned int* counter = (unsigned int*)(partial + (size_t)32 * (size_t)pblk);

    (void)hipMemsetAsync(counter, 0, sizeof(unsigned int), stream);

    bcc_fused<<<NGRP * pblk, 256, 0, stream>>>(
        (const float4*)logit, (const float2*)var, (const int2*)tru,
        (const float4*)noise, partial, counter, out,
        npair, pblk, 1.0f / (float)N);
}

// Round 9
// 66.605 us; speedup vs baseline: 12.9745x; 12.9745x over previous
//
#include <hip/hip_runtime.h>
#include <math.h>

#define TSAMP 30
#define NGRP  5          // t-groups
#define TPG   6          // t's per group (NGRP*TPG == TSAMP)
#define FEPS  1e-15f

// softplus(x) = log1p(exp(x)), stable, 1 exp + 1 log
__device__ __forceinline__ float softplus(float x) {
    return fmaxf(x, 0.0f) + __logf(1.0f + __expf(-fabsf(x)));
}

// Kernel 1 — BODY FROZEN from R7 (65.2 us total, proven).
// NOTE (R5/R6/R8 lesson): NO fused ticket/__threadfence epilogue — agent-scope
// release on gfx950 (non-coherent per-XCD L2s) forces L2 writeback/invalidate
// per wave and collapses codegen to VGPR=28 -> 150 GB/s. 3-kernel structure only.
__global__ __launch_bounds__(256) void bcc_partial(
    const float4* __restrict__ logit4,   // [npair]
    const float2* __restrict__ var2,     // [npair]
    const int2*   __restrict__ true2,    // [npair]
    const float4* __restrict__ noise4,   // [TSAMP][npair]
    float* __restrict__ partial,         // [32][pblk]
    int npair, int pblk)
{
    const int g     = blockIdx.x % NGRP;
    const int pb    = blockIdx.x / NGRP;
    const int tbase = g * TPG;

    float acc[TPG];
    #pragma unroll
    for (int k = 0; k < TPG; ++k) acc[k] = 0.0f;
    float u_acc = 0.0f, vd_acc = 0.0f;

    const int pstride = pblk * 256;
    const float4* nbase = noise4 + (size_t)tbase * (size_t)npair;

    for (int p = pb * 256 + threadIdx.x; p < npair; p += pstride) {
        const float4 lg = logit4[p];
        const float2 v  = var2[p];
        const int2   yy = true2[p];

        // issue all 6 noise loads before the param-dependent math
        float4 nz[TPG];
        #pragma unroll
        for (int k = 0; k < TPG; ++k)
            nz[k] = nbase[(size_t)k * (size_t)npair + p];

        const float sg0 = yy.x ? 1.0f : -1.0f;
        const float d0  = sg0 * (lg.x - lg.y);
        const float ss0 = sg0 * (__fsqrt_rn(v.x) + FEPS);
        const float sg1 = yy.y ? 1.0f : -1.0f;
        const float d1  = sg1 * (lg.z - lg.w);
        const float ss1 = sg1 * (__fsqrt_rn(v.y) + FEPS);

        if (g == 0) {
            vd_acc += (__expf(v.x) - 1.0f) + (__expf(v.y) - 1.0f);
            u_acc  -= softplus(d0) + softplus(d1);
        }

        #pragma unroll
        for (int k = 0; k < TPG; ++k) {
            const float x0 = fmaf(ss0, nz[k].x - nz[k].y, d0);
            const float x1 = fmaf(ss1, nz[k].z - nz[k].w, d1);
            acc[k] -= softplus(x0) + softplus(x1);
        }
    }

    // block-reduce TPG+2 slots (deterministic)
    __shared__ float s_part[4][TPG + 2];
    const int lane = threadIdx.x & 63;
    const int wav  = threadIdx.x >> 6;
    #pragma unroll
    for (int a = 0; a < TPG + 2; ++a) {
        float vv = (a < TPG) ? acc[a] : ((a == TPG) ? u_acc : vd_acc);
        #pragma unroll
        for (int off = 32; off >= 1; off >>= 1)
            vv += __shfl_down(vv, off, 64);
        if (lane == 0) s_part[wav][a] = vv;
    }
    __syncthreads();
    if (threadIdx.x < TPG + 2) {
        const int a = threadIdx.x;
        const float s = s_part[0][a] + s_part[1][a] + s_part[2][a] + s_part[3][a];
        if (a < TPG)
            partial[(size_t)(tbase + a) * (size_t)pblk + pb] = s;
        else if (g == 0)
            partial[(size_t)(TSAMP + (a - TPG)) * (size_t)pblk + pb] = s;
    }
}

// Kernel 2 (merged reduce+epilogue): ONE block, 1024 threads.
// 32 threads per slot; each thread issues pblk/(4*32) independent float4 loads
// (one latency round trip, pipelined); half-wave shfl reduce; thread 0 epilogue.
__global__ __launch_bounds__(1024) void bcc_finish(
    const float* __restrict__ partial,   // [32][pblk]
    int pblk, float invN, float* __restrict__ out)
{
    const int a = threadIdx.x >> 5;          // slot 0..31
    const int j = threadIdx.x & 31;          // lane within slot
    const float* row = partial + (size_t)a * (size_t)pblk;
    float s = 0.0f;
    const int nv = pblk >> 2;
    const float4* row4 = (const float4*)row;
    for (int q = j; q < nv; q += 32) {
        const float4 vv = row4[q];
        s += (vv.x + vv.y) + (vv.z + vv.w);
    }
    for (int q = (nv << 2) + j; q < pblk; q += 32)
        s += row[q];
    #pragma unroll
    for (int off = 16; off >= 1; off >>= 1)
        s += __shfl_down(s, off, 32);
    __shared__ float res[32];
    if (j == 0) res[a] = s;
    __syncthreads();
    if (threadIdx.x == 0) {
        const float U  = -res[30] * invN;          // undistorted_loss
        const float vd =  res[31] * invN;          // mean variance_depressor
        float mc_sum = 0.0f;
        #pragma unroll
        for (int t = 0; t < TSAMP; ++t) {
            const float D = -res[t] * invN;        // distorted_loss[t]
            const float x = U - D;
            const float e = (x > 0.0f) ? x : expm1f(x);   // elu(x)
            mc_sum += -e;                           // monte_carlo[t]
        }
        const float variance_loss = (mc_sum / (float)TSAMP) * U;
        out[0] = variance_loss + U + vd;
    }
}

extern "C" void kernel_launch(void* const* d_in, const int* in_sizes, int n_in,
                              void* d_out, int out_size, void* d_ws, size_t ws_size,
                              hipStream_t stream) {
    const float* logit = (const float*)d_in[0];   // [N,2] f32
    const float* var   = (const float*)d_in[1];   // [N,1] f32
    const int*   tru   = (const int*)d_in[2];     // [N]   i32
    const float* noise = (const float*)d_in[3];   // [30,N,2] f32
    float* out = (float*)d_out;

    const int N = in_sizes[1];          // var has N elements
    const int npair = N / 2;

    // pblk=2048: npair = 2048*256 exactly -> each thread owns ONE pair,
    // all 9 loads issue at kernel entry (max MLP), 2x resident-wave pool.
    int pblk = 2048;
    {
        int maxp = (npair + 255) / 256;
        if (pblk > maxp) pblk = maxp;
        const size_t need = (size_t)32 * (size_t)pblk * sizeof(float);
        if (ws_size < need) {
            pblk = (int)(ws_size / (32 * sizeof(float)));
            if (pblk < 1) pblk = 1;
        }
    }
    float* partial = (float*)d_ws;      // [32][pblk]

    bcc_partial<<<NGRP * pblk, 256, 0, stream>>>(
        (const float4*)logit, (const float2*)var, (const int2*)tru,
        (const float4*)noise, partial, npair, pblk);

    bcc_finish<<<1, 1024, 0, stream>>>(partial, pblk, 1.0f / (float)N, out);
}

// Round 10
// 50.924 us; speedup vs baseline: 16.9698x; 1.3079x over previous
//
#include <hip/hip_runtime.h>
#include <math.h>

#define TSAMP 30
#define RPB   1024       // pairs per block (contiguous range)
#define ITERS (RPB / 256)
#define FEPS  1e-15f

// softplus(x) = log1p(exp(x)), stable, 1 exp + 1 log
__device__ __forceinline__ float softplus(float x) {
    return fmaxf(x, 0.0f) + __logf(1.0f + __expf(-fabsf(x)));
}

// Kernel 1 — LINEAR-STREAM layout: each block owns ONE t-row over a contiguous
// 1024-pair range -> noise reads are a single linear stream per block (the 7 TB/s
// fill pattern). Params are re-read once per (t, range); the XCD swizzle pins all
// 30 t-siblings of a range to one XCD so re-reads hit that XCD's L2 (2 MB/XCD
// working set <= 4 MB L2). Perf-only heuristic; correctness is mapping-free.
// R5/R6/R8 lesson: no fused ticket/__threadfence epilogue (150 GB/s collapse).
__global__ __launch_bounds__(256) void bcc_partial(
    const float4* __restrict__ logit4,   // [npair]
    const float2* __restrict__ var2,     // [npair]
    const int2*   __restrict__ true2,    // [npair]
    const float4* __restrict__ noise4,   // [TSAMP][npair]
    float* __restrict__ partial,         // [32][npr]
    int npair, int npr)
{
    int t, pr;
    if ((npr & 7) == 0) {
        // XCD co-location: bid%8 = XCD (dispatch round-robin heuristic)
        const int x    = blockIdx.x & 7;
        const int slot = blockIdx.x >> 3;
        t  = slot % TSAMP;
        pr = x * (npr >> 3) + slot / TSAMP;
    } else {
        t  = blockIdx.x % TSAMP;
        pr = blockIdx.x / TSAMP;
    }

    const float4* nrow = noise4 + (size_t)t * (size_t)npair;
    const int base = pr * RPB;

    float acc = 0.0f, u_acc = 0.0f, vd_acc = 0.0f;

    #pragma unroll
    for (int it = 0; it < ITERS; ++it) {
        const int p = base + it * 256 + (int)threadIdx.x;
        if (p < npair) {
            const float4 nz = nrow[p];
            const float4 lg = logit4[p];
            const float2 v  = var2[p];
            const int2   yy = true2[p];

            const float sg0 = yy.x ? 1.0f : -1.0f;
            const float d0  = sg0 * (lg.x - lg.y);
            const float ss0 = sg0 * (__fsqrt_rn(v.x) + FEPS);
            const float sg1 = yy.y ? 1.0f : -1.0f;
            const float d1  = sg1 * (lg.z - lg.w);
            const float ss1 = sg1 * (__fsqrt_rn(v.y) + FEPS);

            acc -= softplus(fmaf(ss0, nz.x - nz.y, d0))
                 + softplus(fmaf(ss1, nz.z - nz.w, d1));

            if (t == 0) {   // block-uniform branch
                vd_acc += (__expf(v.x) - 1.0f) + (__expf(v.y) - 1.0f);
                u_acc  -= softplus(d0) + softplus(d1);
            }
        }
    }

    // block-reduce 3 slots (deterministic)
    __shared__ float s_part[4][3];
    const int lane = threadIdx.x & 63;
    const int wav  = threadIdx.x >> 6;
    #pragma unroll
    for (int a = 0; a < 3; ++a) {
        float vv = (a == 0) ? acc : ((a == 1) ? u_acc : vd_acc);
        #pragma unroll
        for (int off = 32; off >= 1; off >>= 1)
            vv += __shfl_down(vv, off, 64);
        if (lane == 0) s_part[wav][a] = vv;
    }
    __syncthreads();
    if (threadIdx.x == 0) {
        const float s0 = s_part[0][0] + s_part[1][0] + s_part[2][0] + s_part[3][0];
        partial[(size_t)t * (size_t)npr + pr] = s0;
        if (t == 0) {
            const float s1 = s_part[0][1] + s_part[1][1] + s_part[2][1] + s_part[3][1];
            const float s2 = s_part[0][2] + s_part[1][2] + s_part[2][2] + s_part[3][2];
            partial[(size_t)30 * (size_t)npr + pr] = s1;
            partial[(size_t)31 * (size_t)npr + pr] = s2;
        }
    }
}

// Kernel 2: 32 blocks, block a reduces partial[a][0..npr) -> res32[a].
__global__ __launch_bounds__(256) void bcc_reduce(
    const float* __restrict__ partial,   // [32][npr]
    int npr, float* __restrict__ res32)  // [32]
{
    const int a = blockIdx.x;
    const float* row = partial + (size_t)a * (size_t)npr;
    float s = 0.0f;
    for (int j = threadIdx.x; j < npr; j += 256)
        s += row[j];
    #pragma unroll
    for (int off = 32; off >= 1; off >>= 1)
        s += __shfl_down(s, off, 64);
    __shared__ float sw[4];
    if ((threadIdx.x & 63) == 0) sw[threadIdx.x >> 6] = s;
    __syncthreads();
    if (threadIdx.x == 0)
        res32[a] = sw[0] + sw[1] + sw[2] + sw[3];
}

// Kernel 3: scalar epilogue on the 32 reduced sums.
__global__ __launch_bounds__(64) void bcc_epilogue(
    const float* __restrict__ res32, float invN, float* __restrict__ out)
{
    if (threadIdx.x == 0) {
        const float U  = -res32[30] * invN;          // undistorted_loss
        const float vd =  res32[31] * invN;          // mean variance_depressor
        float mc_sum = 0.0f;
        #pragma unroll
        for (int t = 0; t < TSAMP; ++t) {
            const float D = -res32[t] * invN;        // distorted_loss[t]
            const float x = U - D;
            const float e = (x > 0.0f) ? x : expm1f(x);   // elu(x)
            mc_sum += -e;                             // monte_carlo[t]
        }
        const float variance_loss = (mc_sum / (float)TSAMP) * U;
        out[0] = variance_loss + U + vd;
    }
}

extern "C" void kernel_launch(void* const* d_in, const int* in_sizes, int n_in,
                              void* d_out, int out_size, void* d_ws, size_t ws_size,
                              hipStream_t stream) {
    const float* logit = (const float*)d_in[0];   // [N,2] f32
    const float* var   = (const float*)d_in[1];   // [N,1] f32
    const int*   tru   = (const int*)d_in[2];     // [N]   i32
    const float* noise = (const float*)d_in[3];   // [30,N,2] f32
    float* out = (float*)d_out;

    const int N = in_sizes[1];          // var has N elements
    const int npair = N / 2;

    int npr = (npair + RPB - 1) / RPB;  // 512 for N=1M
    {
        const size_t need = (size_t)32 * (size_t)npr * sizeof(float) + 32 * sizeof(float);
        if (ws_size < need) {
            // shouldn't happen (64 KB); degrade by growing RPB implicitly is not
            // possible at runtime, so just clamp (correctness preserved by p<npair).
            npr = (int)((ws_size - 32 * sizeof(float)) / (32 * sizeof(float)));
            if (npr < 1) npr = 1;
        }
    }
    float* partial = (float*)d_ws;                       // [32][npr]
    float* res32   = partial + (size_t)32 * (size_t)npr; // [32]

    bcc_partial<<<TSAMP * npr, 256, 0, stream>>>(
        (const float4*)logit, (const float2*)var, (const int2*)tru,
        (const float4*)noise, partial, npair, npr);

    bcc_reduce<<<32, 256, 0, stream>>>(partial, npr, res32);

    bcc_epilogue<<<1, 64, 0, stream>>>(res32, 1.0f / (float)N, out);
}